// Round 1
// baseline (310.568 us; speedup 1.0000x reference)
//
#include <hip/hip_runtime.h>
#include <cstdint>

#define FP8_MAX_F 448.0f

typedef float floatx4 __attribute__((ext_vector_type(4)));

static constexpr int Mdim = 2048;
static constexpr int Ndim = 4096;
static constexpr int Kdim = 4096;
static constexpr int BM = 128;
static constexpr int BN = 128;
static constexpr int BK = 64;  // fp8 bytes of K per staged tile

// ---------------------------------------------------------------------------
// async global->LDS, 16B per lane. LDS dest must be wave-uniform base + lane*16
// (HW constraint) — our flat layout satisfies this: thread t writes LDS byte
// offset t*16 within each 4 KiB chunk.
// ---------------------------------------------------------------------------
__device__ __forceinline__ void async_load16(const void* g, void* l) {
  __builtin_amdgcn_global_load_lds((__attribute__((address_space(1))) void*)g,
                                   (__attribute__((address_space(3))) void*)l,
                                   16, 0, 0);
}

// ---------------------------------------------------------------------------
// Pass 1: per-tensor abs-max. Non-negative floats compare correctly as uints,
// so one u32 atomicMax per block finishes the reduction.
// ---------------------------------------------------------------------------
__global__ void amax_kernel(const float* __restrict__ p, int n4,
                            unsigned int* __restrict__ out_bits) {
  const float4* p4 = (const float4*)p;
  int stride = gridDim.x * blockDim.x;
  float m = 0.f;
  for (int j = blockIdx.x * blockDim.x + threadIdx.x; j < n4; j += stride) {
    float4 v = p4[j];
    m = fmaxf(m, fmaxf(fmaxf(fabsf(v.x), fabsf(v.y)),
                       fmaxf(fabsf(v.z), fabsf(v.w))));
  }
#pragma unroll
  for (int off = 32; off > 0; off >>= 1)
    m = fmaxf(m, __shfl_down(m, off, 64));
  __shared__ float red[4];
  int lane = threadIdx.x & 63;
  int wv = threadIdx.x >> 6;
  if (lane == 0) red[wv] = m;
  __syncthreads();
  if (threadIdx.x == 0) {
    float mm = fmaxf(fmaxf(red[0], red[1]), fmaxf(red[2], red[3]));
    atomicMax(out_bits, __float_as_uint(mm));
  }
}

// ---------------------------------------------------------------------------
// Pass 2: quantize fp32 -> fp8 e4m3fn (OCP — native gfx950 format, RNE via
// v_cvt_pk_fp8_f32, exactly the grid ml_dtypes/jnp float8_e4m3fn uses).
// Mirrors reference: scale = 448/amax (fp32), clip to +-448, round.
// ---------------------------------------------------------------------------
__global__ void quant_kernel(const float* __restrict__ p, int n4,
                             const unsigned int* __restrict__ amax_bits,
                             unsigned int* __restrict__ q) {
  float amax = fmaxf(__uint_as_float(*amax_bits), 1e-12f);
  float scale = FP8_MAX_F / amax;
  const float4* p4 = (const float4*)p;
  int stride = gridDim.x * blockDim.x;
  for (int j = blockIdx.x * blockDim.x + threadIdx.x; j < n4; j += stride) {
    float4 v = p4[j];
    float a = fminf(fmaxf(v.x * scale, -FP8_MAX_F), FP8_MAX_F);
    float b = fminf(fmaxf(v.y * scale, -FP8_MAX_F), FP8_MAX_F);
    float c = fminf(fmaxf(v.z * scale, -FP8_MAX_F), FP8_MAX_F);
    float d = fminf(fmaxf(v.w * scale, -FP8_MAX_F), FP8_MAX_F);
    unsigned int r = 0;
    r = __builtin_amdgcn_cvt_pk_fp8_f32(a, b, r, false);  // bytes 0,1
    r = __builtin_amdgcn_cvt_pk_fp8_f32(c, d, r, true);   // bytes 2,3
    q[j] = r;
  }
}

// ---------------------------------------------------------------------------
// FP8 GEMM, m97 structure: 128x128 tile, BK=64 (two 16x16x32 k-steps per
// staged tile), 256 threads = 4 waves in 2x2, each wave owns a 64x64 C-block
// as 4x4 MFMA tiles. A = qx [M,K], B^T = qw [N,K] (row-major N x K is exactly
// the MFMA B-fragment layout for mk,nk->mn).
// Fragment layouts (HW-verified, learn_hip m89):
//   A: lane holds A[m=lane&15][k=(lane>>4)*8 + j], j=0..7 (8 consecutive bytes)
//   C/D: col = lane&15, row = (lane>>4)*4 + reg
// Epilogue fused: out = acc * (1/scale_x)*(1/scale_w) + bias[n].
// ---------------------------------------------------------------------------
__launch_bounds__(256, 2)
__global__ void gemm_fp8(const unsigned char* __restrict__ qx,
                         const unsigned char* __restrict__ qw,
                         const float* __restrict__ bias,
                         const unsigned int* __restrict__ amax_x_bits,
                         const unsigned int* __restrict__ amax_w_bits,
                         float* __restrict__ out) {
  __shared__ __align__(16) unsigned char As[BM * BK];  // 8 KiB, [128][64] row-major, no pad (global_load_lds)
  __shared__ __align__(16) unsigned char Bs[BN * BK];  // 8 KiB

  const int tid = threadIdx.x;
  const int lane = tid & 63;
  const int wv = tid >> 6;
  const int wm = (wv & 1) * 64;   // wave row offset in tile
  const int wn = (wv >> 1) * 64;  // wave col offset in tile
  const int bm0 = blockIdx.y * BM;
  const int bn0 = blockIdx.x * BN;

  // Staging: thread t covers LDS flat bytes [t*16, t*16+16) of each 4 KiB
  // half-tile; source row = t>>2 (+64 for second half), col = (t&3)*16.
  const int srow = tid >> 2;
  const int scol = (tid & 3) * 16;
  const unsigned char* ga0 = qx + (size_t)(bm0 + srow) * Kdim + scol;
  const unsigned char* ga1 = qx + (size_t)(bm0 + 64 + srow) * Kdim + scol;
  const unsigned char* gb0 = qw + (size_t)(bn0 + srow) * Kdim + scol;
  const unsigned char* gb1 = qw + (size_t)(bn0 + 64 + srow) * Kdim + scol;
  unsigned char* la0 = As + tid * 16;
  unsigned char* la1 = As + 4096 + tid * 16;
  unsigned char* lb0 = Bs + tid * 16;
  unsigned char* lb1 = Bs + 4096 + tid * 16;

  floatx4 acc[4][4];
#pragma unroll
  for (int i = 0; i < 4; i++)
#pragma unroll
    for (int j = 0; j < 4; j++) acc[i][j] = (floatx4){0.f, 0.f, 0.f, 0.f};

  const int frow = lane & 15;        // m (or n) within 16x16 tile
  const int fq = (lane >> 4) * 8;    // k byte offset within 32-wide k-step

  for (int k0 = 0; k0 < Kdim; k0 += BK) {
    async_load16(ga0 + k0, la0);
    async_load16(ga1 + k0, la1);
    async_load16(gb0 + k0, lb0);
    async_load16(gb1 + k0, lb1);
    __syncthreads();  // compiler emits vmcnt(0) drain before s_barrier

#pragma unroll
    for (int ks = 0; ks < 2; ks++) {
      long long af[4], bf[4];
#pragma unroll
      for (int t = 0; t < 4; t++) {
        af[t] = *(const long long*)(As + (wm + t * 16 + frow) * BK + ks * 32 + fq);
        bf[t] = *(const long long*)(Bs + (wn + t * 16 + frow) * BK + ks * 32 + fq);
      }
#pragma unroll
      for (int i = 0; i < 4; i++)
#pragma unroll
        for (int j = 0; j < 4; j++)
          acc[i][j] = __builtin_amdgcn_mfma_f32_16x16x32_fp8_fp8(
              af[i], bf[j], acc[i][j], 0, 0, 0);
    }
    __syncthreads();
  }

  // Combined dequant scale, mirroring reference fp32 arithmetic:
  // x_scale = 1/(448/amax_x); w_scale = 1/(448/amax_w); factor = x_scale*w_scale
  float ax = fmaxf(__uint_as_float(*amax_x_bits), 1e-12f);
  float aw = fmaxf(__uint_as_float(*amax_w_bits), 1e-12f);
  float cs = (1.0f / (FP8_MAX_F / ax)) * (1.0f / (FP8_MAX_F / aw));

  const int crow = bm0 + wm + (lane >> 4) * 4;
  const int ccol = bn0 + wn + (lane & 15);
#pragma unroll
  for (int j = 0; j < 4; j++) {
    float bv = bias[ccol + j * 16];
#pragma unroll
    for (int i = 0; i < 4; i++) {
#pragma unroll
      for (int r = 0; r < 4; r++) {
        out[(size_t)(crow + i * 16 + r) * Ndim + (ccol + j * 16)] =
            acc[i][j][r] * cs + bv;
      }
    }
  }
}

extern "C" void kernel_launch(void* const* d_in, const int* in_sizes, int n_in,
                              void* d_out, int out_size, void* d_ws, size_t ws_size,
                              hipStream_t stream) {
  const float* x = (const float*)d_in[0];     // [M,K] fp32
  const float* w = (const float*)d_in[1];     // [N,K] fp32
  const float* bias = (const float*)d_in[2];  // [N] fp32
  float* out = (float*)d_out;                 // [M,N] fp32

  // Workspace layout: [0]=amax_x bits, [1]=amax_w bits, 256B pad, qx, qw
  unsigned int* amax_x = (unsigned int*)d_ws;
  unsigned int* amax_w = amax_x + 1;
  unsigned char* qx = (unsigned char*)d_ws + 256;
  unsigned char* qw = qx + (size_t)Mdim * Kdim;

  hipMemsetAsync(d_ws, 0, 8, stream);  // zero amax slots (ws is 0xAA-poisoned)

  const int n4x = Mdim * Kdim / 4;
  const int n4w = Ndim * Kdim / 4;
  amax_kernel<<<512, 256, 0, stream>>>(x, n4x, amax_x);
  amax_kernel<<<1024, 256, 0, stream>>>(w, n4w, amax_w);
  quant_kernel<<<512, 256, 0, stream>>>(x, n4x, amax_x, (unsigned int*)qx);
  quant_kernel<<<1024, 256, 0, stream>>>(w, n4w, amax_w, (unsigned int*)qw);

  dim3 grid(Ndim / BN, Mdim / BM);  // 32 x 16 = 512 blocks
  gemm_fp8<<<grid, 256, 0, stream>>>(qx, qw, bias, amax_x, amax_w, out);
}

// Round 2
// 227.441 us; speedup vs baseline: 1.3655x; 1.3655x over previous
//
#include <hip/hip_runtime.h>
#include <cstdint>

#define FP8_MAX_F 448.0f

typedef float floatx4 __attribute__((ext_vector_type(4)));

static constexpr int Mdim = 2048;
static constexpr int Ndim = 4096;
static constexpr int Kdim = 4096;
static constexpr int BM = 128;
static constexpr int BN = 128;
static constexpr int BK = 64;  // fp8 bytes of K per staged tile

// ---------------------------------------------------------------------------
// async global->LDS, 16B per lane. LDS dest is wave-uniform base + lane*16
// (HW constraint) — thread t always writes LDS byte offset t*16 in its chunk;
// we pick WHICH global 16B it fetches to realize the XOR-swizzled layout.
// ---------------------------------------------------------------------------
__device__ __forceinline__ void async_load16(const void* g, void* l) {
  __builtin_amdgcn_global_load_lds((__attribute__((address_space(1))) void*)g,
                                   (__attribute__((address_space(3))) void*)l,
                                   16, 0, 0);
}

// ---------------------------------------------------------------------------
// Fused per-tensor abs-max for BOTH tensors in one dispatch (x-blocks and
// w-blocks run concurrently instead of as two serialized launches).
// Non-negative floats compare correctly as uints -> one u32 atomicMax/block.
// ---------------------------------------------------------------------------
static constexpr int AXB = 1024;   // blocks for x
static constexpr int AWB = 2048;   // blocks for w

__global__ void amax_both(const float* __restrict__ x, int n4x,
                          const float* __restrict__ w, int n4w,
                          unsigned int* __restrict__ ax_bits,
                          unsigned int* __restrict__ aw_bits) {
  const float4* p4;
  int n4, bid, nb;
  unsigned int* out_bits;
  if (blockIdx.x < AXB) {
    p4 = (const float4*)x; n4 = n4x; bid = blockIdx.x; nb = AXB; out_bits = ax_bits;
  } else {
    p4 = (const float4*)w; n4 = n4w; bid = blockIdx.x - AXB; nb = AWB; out_bits = aw_bits;
  }
  int stride = nb * blockDim.x;
  float m = 0.f;
  for (int j = bid * blockDim.x + threadIdx.x; j < n4; j += stride) {
    float4 v = p4[j];
    m = fmaxf(m, fmaxf(fmaxf(fabsf(v.x), fabsf(v.y)),
                       fmaxf(fabsf(v.z), fabsf(v.w))));
  }
#pragma unroll
  for (int off = 32; off > 0; off >>= 1)
    m = fmaxf(m, __shfl_down(m, off, 64));
  __shared__ float red[4];
  int lane = threadIdx.x & 63;
  int wv = threadIdx.x >> 6;
  if (lane == 0) red[wv] = m;
  __syncthreads();
  if (threadIdx.x == 0) {
    float mm = fmaxf(fmaxf(red[0], red[1]), fmaxf(red[2], red[3]));
    atomicMax(out_bits, __float_as_uint(mm));
  }
}

// ---------------------------------------------------------------------------
// Fused quantize of BOTH tensors: fp32 -> fp8 e4m3fn (native gfx950 OCP grid,
// RNE via v_cvt_pk_fp8_f32 — same grid as jnp float8_e4m3fn).
// Mirrors reference: scale = 448/amax (fp32), clip to +-448, round.
// ---------------------------------------------------------------------------
__global__ void quant_both(const float* __restrict__ x, int n4x,
                           const float* __restrict__ w, int n4w,
                           const unsigned int* __restrict__ ax_bits,
                           const unsigned int* __restrict__ aw_bits,
                           unsigned int* __restrict__ qx,
                           unsigned int* __restrict__ qw) {
  const float4* p4;
  int n4, bid, nb;
  unsigned int* q;
  const unsigned int* ab;
  if (blockIdx.x < AXB) {
    p4 = (const float4*)x; n4 = n4x; bid = blockIdx.x; nb = AXB; q = qx; ab = ax_bits;
  } else {
    p4 = (const float4*)w; n4 = n4w; bid = blockIdx.x - AXB; nb = AWB; q = qw; ab = aw_bits;
  }
  float amax = fmaxf(__uint_as_float(*ab), 1e-12f);
  float scale = FP8_MAX_F / amax;
  int stride = nb * blockDim.x;
  for (int j = bid * blockDim.x + threadIdx.x; j < n4; j += stride) {
    float4 v = p4[j];
    float a = fminf(fmaxf(v.x * scale, -FP8_MAX_F), FP8_MAX_F);
    float b = fminf(fmaxf(v.y * scale, -FP8_MAX_F), FP8_MAX_F);
    float c = fminf(fmaxf(v.z * scale, -FP8_MAX_F), FP8_MAX_F);
    float d = fminf(fmaxf(v.w * scale, -FP8_MAX_F), FP8_MAX_F);
    unsigned int r = 0;
    r = __builtin_amdgcn_cvt_pk_fp8_f32(a, b, r, false);  // bytes 0,1
    r = __builtin_amdgcn_cvt_pk_fp8_f32(c, d, r, true);   // bytes 2,3
    q[j] = r;
  }
}

// ---------------------------------------------------------------------------
// FP8 GEMM, m97 structure: 128x128 tile, BK=64 (two 16x16x32 k-steps per
// staged tile), 256 threads = 4 waves 2x2, each wave a 64x64 C-block of 4x4
// MFMA tiles. A = qx [M,K], B^T = qw [N,K].
//
// LDS bank-conflict fix (R1): XOR-swizzled layout at 16B granularity.
//   logical (row r, chunk c)  ->  physical chunk  c ^ ((r>>1)&3)
// Staging side: thread t (fixed LDS slot t*16 = row t>>2, phys chunk t&3)
// fetches global chunk (t&3) ^ ((t>>3)&3).  Read side: tile-row bases are
// multiples of 16, so the swizzle term is the lane constant (frow>>1)&3.
// Quad's 16 rows now spread over 8 bank-pairs (2-way, free) vs 1 (8-way).
//
// Fragment layouts (HW-verified, learn_hip m89):
//   A: lane holds A[m=lane&15][k=(lane>>4)*8 + j], j=0..7
//   C/D: col = lane&15, row = (lane>>4)*4 + reg
// ---------------------------------------------------------------------------
__launch_bounds__(256, 2)
__global__ void gemm_fp8(const unsigned char* __restrict__ qx,
                         const unsigned char* __restrict__ qw,
                         const float* __restrict__ bias,
                         const unsigned int* __restrict__ amax_x_bits,
                         const unsigned int* __restrict__ amax_w_bits,
                         float* __restrict__ out) {
  __shared__ __align__(16) unsigned char As[BM * BK];  // 8 KiB
  __shared__ __align__(16) unsigned char Bs[BN * BK];  // 8 KiB

  const int tid = threadIdx.x;
  const int lane = tid & 63;
  const int wv = tid >> 6;
  const int wm = (wv & 1) * 64;
  const int wn = (wv >> 1) * 64;
  const int bm0 = blockIdx.y * BM;
  const int bn0 = blockIdx.x * BN;

  // Staging: thread t owns LDS slot t*16 (row srow=t>>2, phys chunk t&3).
  // Global col chunk = (t&3) ^ s(srow), s(r) = (r>>1)&3  (same for row+64).
  const int srow = tid >> 2;
  const int scol = (((tid & 3) ^ ((srow >> 1) & 3)) * 16);
  const unsigned char* ga0 = qx + (size_t)(bm0 + srow) * Kdim + scol;
  const unsigned char* ga1 = qx + (size_t)(bm0 + 64 + srow) * Kdim + scol;
  const unsigned char* gb0 = qw + (size_t)(bn0 + srow) * Kdim + scol;
  const unsigned char* gb1 = qw + (size_t)(bn0 + 64 + srow) * Kdim + scol;
  unsigned char* la0 = As + tid * 16;
  unsigned char* la1 = As + 4096 + tid * 16;
  unsigned char* lb0 = Bs + tid * 16;
  unsigned char* lb1 = Bs + 4096 + tid * 16;

  floatx4 acc[4][4];
#pragma unroll
  for (int i = 0; i < 4; i++)
#pragma unroll
    for (int j = 0; j < 4; j++) acc[i][j] = (floatx4){0.f, 0.f, 0.f, 0.f};

  // Fragment read constants (lane-only, hoisted out of K-loop):
  const int frow = lane & 15;            // m (or n) within 16x16 tile
  const int sw = (frow >> 1) & 3;        // row-swizzle term (base rows %16==0)
  const int cbase = lane >> 5;           // chunk contribution of quad
  const int koff8 = ((lane >> 4) & 1) * 8;  // 8B offset within 16B chunk

  for (int k0 = 0; k0 < Kdim; k0 += BK) {
    async_load16(ga0 + k0, la0);
    async_load16(ga1 + k0, la1);
    async_load16(gb0 + k0, lb0);
    async_load16(gb1 + k0, lb1);
    __syncthreads();

#pragma unroll
    for (int ks = 0; ks < 2; ks++) {
      const int physk = (((ks * 2 + cbase) ^ sw) << 4) + koff8;
      long long af[4], bf[4];
#pragma unroll
      for (int t = 0; t < 4; t++) {
        af[t] = *(const long long*)(As + (wm + t * 16 + frow) * BK + physk);
        bf[t] = *(const long long*)(Bs + (wn + t * 16 + frow) * BK + physk);
      }
#pragma unroll
      for (int i = 0; i < 4; i++)
#pragma unroll
        for (int j = 0; j < 4; j++)
          acc[i][j] = __builtin_amdgcn_mfma_f32_16x16x32_fp8_fp8(
              af[i], bf[j], acc[i][j], 0, 0, 0);
    }
    __syncthreads();
  }

  // Combined dequant scale, mirroring reference fp32 arithmetic.
  float ax = fmaxf(__uint_as_float(*amax_x_bits), 1e-12f);
  float aw = fmaxf(__uint_as_float(*amax_w_bits), 1e-12f);
  float cs = (1.0f / (FP8_MAX_F / ax)) * (1.0f / (FP8_MAX_F / aw));

  const int crow = bm0 + wm + (lane >> 4) * 4;
  const int ccol = bn0 + wn + (lane & 15);
#pragma unroll
  for (int j = 0; j < 4; j++) {
    float bv = bias[ccol + j * 16];
#pragma unroll
    for (int i = 0; i < 4; i++) {
#pragma unroll
      for (int r = 0; r < 4; r++) {
        out[(size_t)(crow + i * 16 + r) * Ndim + (ccol + j * 16)] =
            acc[i][j][r] * cs + bv;
      }
    }
  }
}

extern "C" void kernel_launch(void* const* d_in, const int* in_sizes, int n_in,
                              void* d_out, int out_size, void* d_ws, size_t ws_size,
                              hipStream_t stream) {
  const float* x = (const float*)d_in[0];     // [M,K] fp32
  const float* w = (const float*)d_in[1];     // [N,K] fp32
  const float* bias = (const float*)d_in[2];  // [N] fp32
  float* out = (float*)d_out;                 // [M,N] fp32

  // Workspace: [0]=amax_x bits, [1]=amax_w bits, 256B pad, qx, qw
  unsigned int* amax_x = (unsigned int*)d_ws;
  unsigned int* amax_w = amax_x + 1;
  unsigned char* qx = (unsigned char*)d_ws + 256;
  unsigned char* qw = qx + (size_t)Mdim * Kdim;

  hipMemsetAsync(d_ws, 0, 8, stream);  // zero amax slots (ws is 0xAA-poisoned)

  const int n4x = Mdim * Kdim / 4;
  const int n4w = Ndim * Kdim / 4;
  amax_both<<<AXB + AWB, 256, 0, stream>>>(x, n4x, w, n4w, amax_x, amax_w);
  quant_both<<<AXB + AWB, 256, 0, stream>>>(x, n4x, w, n4w, amax_x, amax_w,
                                            (unsigned int*)qx, (unsigned int*)qw);

  dim3 grid(Ndim / BN, Mdim / BM);  // 32 x 16 = 512 blocks
  gemm_fp8<<<grid, 256, 0, stream>>>(qx, qw, bias, amax_x, amax_w, out);
}

// Round 3
// 181.705 us; speedup vs baseline: 1.7092x; 1.2517x over previous
//
#include <hip/hip_runtime.h>
#include <cstdint>

#define FP8_MAX_F 448.0f

typedef float floatx4 __attribute__((ext_vector_type(4)));
typedef int   intx4   __attribute__((ext_vector_type(4)));
typedef int   intx8   __attribute__((ext_vector_type(8)));

static constexpr int Mdim = 2048;
static constexpr int Ndim = 4096;
static constexpr int Kdim = 4096;
static constexpr int BM = 128;
static constexpr int BN = 128;
static constexpr int BK = 128;  // fp8 bytes of K per staged tile (one K=128 MFMA)

// amax/quant grids: exact cover, 1024 float4 per block (4 per thread, no loop)
static constexpr int XB = 2048;  // Mdim*Kdim/4 / 1024
static constexpr int WB = 4096;  // Ndim*Kdim/4 / 1024

__device__ __forceinline__ void async_load16(const void* g, void* l) {
  __builtin_amdgcn_global_load_lds((__attribute__((address_space(1))) void*)g,
                                   (__attribute__((address_space(3))) void*)l,
                                   16, 0, 0);
}

// ---------------------------------------------------------------------------
// Pass 1: per-block partial abs-max, both tensors in one dispatch.
// 4 independent float4 loads per thread (4 outstanding -> latency-proof),
// no grid-stride loop, no atomics (each block writes its own partial slot).
// ---------------------------------------------------------------------------
__global__ void amax_partials(const float* __restrict__ x,
                              const float* __restrict__ w,
                              float* __restrict__ part) {
  const int b = blockIdx.x;
  const float4* p4;
  float* dst;
  int bid;
  if (b < XB) { p4 = (const float4*)x; dst = part;      bid = b; }
  else        { p4 = (const float4*)w; dst = part + XB; bid = b - XB; }
  const int tid = threadIdx.x;
  const int base = bid * 1024 + tid;
  float4 v0 = p4[base];
  float4 v1 = p4[base + 256];
  float4 v2 = p4[base + 512];
  float4 v3 = p4[base + 768];
  float m = fmaxf(fmaxf(fmaxf(fabsf(v0.x), fabsf(v0.y)), fmaxf(fabsf(v0.z), fabsf(v0.w))),
                  fmaxf(fmaxf(fabsf(v1.x), fabsf(v1.y)), fmaxf(fabsf(v1.z), fabsf(v1.w))));
  m = fmaxf(m, fmaxf(fmaxf(fabsf(v2.x), fabsf(v2.y)), fmaxf(fabsf(v2.z), fabsf(v2.w))));
  m = fmaxf(m, fmaxf(fmaxf(fabsf(v3.x), fabsf(v3.y)), fmaxf(fabsf(v3.z), fabsf(v3.w))));
#pragma unroll
  for (int off = 32; off > 0; off >>= 1)
    m = fmaxf(m, __shfl_down(m, off, 64));
  __shared__ float red[4];
  if ((tid & 63) == 0) red[tid >> 6] = m;
  __syncthreads();
  if (tid == 0)
    dst[bid] = fmaxf(fmaxf(red[0], red[1]), fmaxf(red[2], red[3]));
}

// ---------------------------------------------------------------------------
// Pass 2: reduce partials -> per-tensor amax (block 0 publishes the scalar),
// then quantize fp32 -> fp8 e4m3fn (native OCP grid, RNE via v_cvt_pk_fp8_f32
// — same grid as jnp float8_e4m3fn). Mirrors reference fp32 arithmetic:
// amax = max(|t|, 1e-12); scale = 448/amax; clip; round.
// ---------------------------------------------------------------------------
__global__ void quant_both(const float* __restrict__ x,
                           const float* __restrict__ w,
                           const float* __restrict__ part,
                           unsigned int* __restrict__ qx,
                           unsigned int* __restrict__ qw,
                           float* __restrict__ scalars) {
  const int b = blockIdx.x;
  const float4* p4;
  const float* po;
  unsigned int* q;
  float* slot;
  int np, bid;
  if (b < XB) { p4 = (const float4*)x; po = part;      q = qx; np = XB; bid = b;      slot = scalars;     }
  else        { p4 = (const float4*)w; po = part + XB; q = qw; np = WB; bid = b - XB; slot = scalars + 1; }
  const int tid = threadIdx.x;

  float m = 0.f;
  for (int i = tid; i < np; i += 256) m = fmaxf(m, po[i]);
#pragma unroll
  for (int off = 32; off > 0; off >>= 1)
    m = fmaxf(m, __shfl_down(m, off, 64));
  __shared__ float red[4];
  __shared__ float amax_s;
  if ((tid & 63) == 0) red[tid >> 6] = m;
  __syncthreads();
  if (tid == 0) {
    float mm = fmaxf(fmaxf(fmaxf(red[0], red[1]), fmaxf(red[2], red[3])), 1e-12f);
    amax_s = mm;
    if (bid == 0) *slot = mm;  // publish for gemm epilogue
  }
  __syncthreads();
  const float scale = FP8_MAX_F / amax_s;

  const int base = bid * 1024 + tid;
#pragma unroll
  for (int u = 0; u < 4; u++) {
    float4 v = p4[base + u * 256];
    float a = fminf(fmaxf(v.x * scale, -FP8_MAX_F), FP8_MAX_F);
    float bb = fminf(fmaxf(v.y * scale, -FP8_MAX_F), FP8_MAX_F);
    float c = fminf(fmaxf(v.z * scale, -FP8_MAX_F), FP8_MAX_F);
    float d = fminf(fmaxf(v.w * scale, -FP8_MAX_F), FP8_MAX_F);
    unsigned int r = 0;
    r = __builtin_amdgcn_cvt_pk_fp8_f32(a, bb, r, false);
    r = __builtin_amdgcn_cvt_pk_fp8_f32(c, d, r, true);
    q[base + u * 256] = r;
  }
}

// ---------------------------------------------------------------------------
// FP8 GEMM at the full fp8 rate: block-scaled mfma_scale_f32_16x16x128_f8f6f4
// with UNIT scales (e8m0 0x7F = 2^0) — numerically plain fp8 dot + fp32 acc,
// but 2x the MFMA throughput of the non-scaled 16x16x32 (m145->m148).
// 128x128 tile, BK=128 (one MFMA per tile-pair per K-tile), 4 waves 2x2,
// each wave 64x64 = 4x4 MFMA tiles.
//
// LDS layout: rows of 128B = 8 chunks of 16B, XOR-swizzled:
//   logical chunk c of row r lives at physical chunk c ^ (r&7).
// Staging (global_load_lds pins LDS dst to tid*16): load l, thread t owns
// flat chunk l*256+t -> row r = l*32 + (t>>3), phys chunk t&7, so it fetches
// global chunk (t&7) ^ (r&7) = (t&7) ^ ((t>>3)&7) (lane constant).
// Read side: fragment rows are base(mult of 16)+frow -> swizzle term frow&7.
//
// Fragment layouts (16x16 family, HW-verified m89/m148):
//   A: lane holds A[m=lane&15][k=(lane>>4)*32 + j], j=0..31 (32 consecutive B)
//   C/D: col = lane&15, row = (lane>>4)*4 + reg   (shape-determined)
// ---------------------------------------------------------------------------
__launch_bounds__(256, 2)
__global__ void gemm_fp8(const unsigned char* __restrict__ qx,
                         const unsigned char* __restrict__ qw,
                         const float* __restrict__ bias,
                         const float* __restrict__ scalars,
                         float* __restrict__ out) {
  __shared__ __align__(16) unsigned char As[BM * BK];  // 16 KiB
  __shared__ __align__(16) unsigned char Bs[BN * BK];  // 16 KiB

  const int tid = threadIdx.x;
  const int lane = tid & 63;
  const int wv = tid >> 6;
  const int wm = (wv & 1) * 64;
  const int wn = (wv >> 1) * 64;
  const int bm0 = blockIdx.y * BM;
  const int bn0 = blockIdx.x * BN;

  // Staging source map (lane constants)
  const int srow = tid >> 3;                              // 0..31, +32 per load l
  const int sc = (((tid & 7) ^ ((tid >> 3) & 7)) << 4);   // swizzled source col
  const unsigned char* gA = qx + (size_t)bm0 * Kdim;
  const unsigned char* gB = qw + (size_t)bn0 * Kdim;

  floatx4 acc[4][4];
#pragma unroll
  for (int i = 0; i < 4; i++)
#pragma unroll
    for (int j = 0; j < 4; j++) acc[i][j] = (floatx4){0.f, 0.f, 0.f, 0.f};

  // Fragment read constants
  const int frow = lane & 15;
  const int h = lane >> 4;              // k-block 0..3 (32 bytes each)
  const int fr7 = frow & 7;
  const int kc0 = (((2 * h) ^ fr7) << 4);      // phys offset of logical chunk 2h
  const int kc1 = (((2 * h + 1) ^ fr7) << 4);  // phys offset of logical chunk 2h+1

  for (int k0 = 0; k0 < Kdim; k0 += BK) {
#pragma unroll
    for (int l = 0; l < 4; l++) {
      async_load16(gA + (size_t)(l * 32 + srow) * Kdim + k0 + sc, As + l * 4096 + tid * 16);
      async_load16(gB + (size_t)(l * 32 + srow) * Kdim + k0 + sc, Bs + l * 4096 + tid * 16);
    }
    __syncthreads();

    intx8 af[4], bf[4];
#pragma unroll
    for (int t = 0; t < 4; t++) {
      const unsigned char* ra = As + (wm + t * 16 + frow) * BK;
      const unsigned char* rb = Bs + (wn + t * 16 + frow) * BK;
      intx4 alo = *(const intx4*)(ra + kc0);
      intx4 ahi = *(const intx4*)(ra + kc1);
      intx4 blo = *(const intx4*)(rb + kc0);
      intx4 bhi = *(const intx4*)(rb + kc1);
      af[t] = __builtin_shufflevector(alo, ahi, 0, 1, 2, 3, 4, 5, 6, 7);
      bf[t] = __builtin_shufflevector(blo, bhi, 0, 1, 2, 3, 4, 5, 6, 7);
    }
#pragma unroll
    for (int i = 0; i < 4; i++)
#pragma unroll
      for (int j = 0; j < 4; j++)
        acc[i][j] = __builtin_amdgcn_mfma_scale_f32_16x16x128_f8f6f4(
            af[i], bf[j], acc[i][j], 0 /*A=fp8*/, 0 /*B=fp8*/,
            0, 0x7F7F7F7F, 0, 0x7F7F7F7F);  // unit scales (e8m0 127 = 2^0)
    __syncthreads();
  }

  // Dequant scale, mirroring reference fp32 arithmetic exactly.
  float ax = fmaxf(scalars[0], 1e-12f);
  float aw = fmaxf(scalars[1], 1e-12f);
  float cs = (1.0f / (FP8_MAX_F / ax)) * (1.0f / (FP8_MAX_F / aw));

  const int crow = bm0 + wm + (lane >> 4) * 4;
  const int ccol = bn0 + wn + (lane & 15);
#pragma unroll
  for (int j = 0; j < 4; j++) {
    float bv = bias[ccol + j * 16];
#pragma unroll
    for (int i = 0; i < 4; i++) {
#pragma unroll
      for (int r = 0; r < 4; r++) {
        out[(size_t)(crow + i * 16 + r) * Ndim + (ccol + j * 16)] =
            acc[i][j][r] * cs + bv;
      }
    }
  }
}

extern "C" void kernel_launch(void* const* d_in, const int* in_sizes, int n_in,
                              void* d_out, int out_size, void* d_ws, size_t ws_size,
                              hipStream_t stream) {
  const float* x = (const float*)d_in[0];     // [M,K] fp32
  const float* w = (const float*)d_in[1];     // [N,K] fp32
  const float* bias = (const float*)d_in[2];  // [N] fp32
  float* out = (float*)d_out;                 // [M,N] fp32

  // Workspace: partials (6144 f) | scalars (2 f) | pad to 32 KiB | qx | qw
  float* part = (float*)d_ws;
  float* scalars = part + XB + WB;
  unsigned char* qx = (unsigned char*)d_ws + 32768;
  unsigned char* qw = qx + (size_t)Mdim * Kdim;

  amax_partials<<<XB + WB, 256, 0, stream>>>(x, w, part);
  quant_both<<<XB + WB, 256, 0, stream>>>(x, w, part,
                                          (unsigned int*)qx, (unsigned int*)qw,
                                          scalars);
  dim3 grid(Ndim / BN, Mdim / BM);  // 32 x 16 = 512 blocks
  gemm_fp8<<<grid, 256, 0, stream>>>(qx, qw, bias, scalars, out);
}

// Round 4
// 180.285 us; speedup vs baseline: 1.7227x; 1.0079x over previous
//
#include <hip/hip_runtime.h>
#include <cstdint>

#define FP8_MAX_F 448.0f

typedef float floatx4 __attribute__((ext_vector_type(4)));
typedef int   intx4   __attribute__((ext_vector_type(4)));
typedef int   intx8   __attribute__((ext_vector_type(8)));

static constexpr int Mdim = 2048;
static constexpr int Ndim = 4096;
static constexpr int Kdim = 4096;
static constexpr int BM = 128;
static constexpr int BN = 128;
static constexpr int BK = 128;   // fp8 bytes of K per staged tile
static constexpr int KT = Kdim / BK;  // 32 K-iterations

// amax: 8 float4 per thread (8 outstanding loads), exact cover
static constexpr int A_XB = 1024;  // 2048*4096/4 / 2048
static constexpr int A_WB = 2048;  // 4096*4096/4 / 2048
// quant: 4 float4 per thread, exact cover
static constexpr int Q_XB = 2048;
static constexpr int Q_WB = 4096;

__device__ __forceinline__ void async_load16(const void* g, void* l) {
  __builtin_amdgcn_global_load_lds((__attribute__((address_space(1))) void*)g,
                                   (__attribute__((address_space(3))) void*)l,
                                   16, 0, 0);
}

// ---------------------------------------------------------------------------
// Pass 1: per-block partial abs-max, both tensors in one dispatch.
// 8 independent float4 loads/thread; per-block partial slot (no atomics).
// ---------------------------------------------------------------------------
__global__ void amax_partials(const float* __restrict__ x,
                              const float* __restrict__ w,
                              float* __restrict__ part) {
  const int b = blockIdx.x;
  const float4* p4;
  float* dst;
  int bid;
  if (b < A_XB) { p4 = (const float4*)x; dst = part;        bid = b; }
  else          { p4 = (const float4*)w; dst = part + A_XB; bid = b - A_XB; }
  const int tid = threadIdx.x;
  const int base = bid * 2048 + tid;
  float4 v[8];
#pragma unroll
  for (int u = 0; u < 8; u++) v[u] = p4[base + u * 256];
  float m = 0.f;
#pragma unroll
  for (int u = 0; u < 8; u++)
    m = fmaxf(m, fmaxf(fmaxf(fabsf(v[u].x), fabsf(v[u].y)),
                       fmaxf(fabsf(v[u].z), fabsf(v[u].w))));
#pragma unroll
  for (int off = 32; off > 0; off >>= 1)
    m = fmaxf(m, __shfl_down(m, off, 64));
  __shared__ float red[4];
  if ((tid & 63) == 0) red[tid >> 6] = m;
  __syncthreads();
  if (tid == 0)
    dst[bid] = fmaxf(fmaxf(red[0], red[1]), fmaxf(red[2], red[3]));
}

// ---------------------------------------------------------------------------
// Pass 2: reduce partials -> per-tensor amax (block 0 of each tensor also
// publishes the scalar for the gemm epilogue), then quantize fp32 -> fp8
// e4m3fn (native OCP grid, RNE via v_cvt_pk_fp8_f32 — the same grid as
// jnp float8_e4m3fn). Mirrors reference fp32 arithmetic exactly:
// amax = max(|t|, 1e-12); scale = 448/amax; clip to +-448; round.
// ---------------------------------------------------------------------------
__global__ void quant_both(const float* __restrict__ x,
                           const float* __restrict__ w,
                           const float* __restrict__ part,
                           unsigned int* __restrict__ qx,
                           unsigned int* __restrict__ qw,
                           float* __restrict__ scalars) {
  const int b = blockIdx.x;
  const float4* p4;
  const float* po;
  unsigned int* q;
  float* slot;
  int np, bid;
  if (b < Q_XB) { p4 = (const float4*)x; po = part;        q = qx; np = A_XB; bid = b;        slot = scalars;     }
  else          { p4 = (const float4*)w; po = part + A_XB; q = qw; np = A_WB; bid = b - Q_XB; slot = scalars + 1; }
  const int tid = threadIdx.x;

  float m = 0.f;
  for (int i = tid; i < np; i += 256) m = fmaxf(m, po[i]);
#pragma unroll
  for (int off = 32; off > 0; off >>= 1)
    m = fmaxf(m, __shfl_down(m, off, 64));
  __shared__ float red[4];
  __shared__ float amax_s;
  if ((tid & 63) == 0) red[tid >> 6] = m;
  __syncthreads();
  if (tid == 0) {
    float mm = fmaxf(fmaxf(fmaxf(red[0], red[1]), fmaxf(red[2], red[3])), 1e-12f);
    amax_s = mm;
    if (bid == 0) *slot = mm;
  }
  __syncthreads();
  const float scale = FP8_MAX_F / amax_s;

  const int base = bid * 1024 + tid;
#pragma unroll
  for (int u = 0; u < 4; u++) {
    float4 v = p4[base + u * 256];
    float a = fminf(fmaxf(v.x * scale, -FP8_MAX_F), FP8_MAX_F);
    float bb = fminf(fmaxf(v.y * scale, -FP8_MAX_F), FP8_MAX_F);
    float c = fminf(fmaxf(v.z * scale, -FP8_MAX_F), FP8_MAX_F);
    float d = fminf(fmaxf(v.w * scale, -FP8_MAX_F), FP8_MAX_F);
    unsigned int r = 0;
    r = __builtin_amdgcn_cvt_pk_fp8_f32(a, bb, r, false);
    r = __builtin_amdgcn_cvt_pk_fp8_f32(c, d, r, true);
    q[base + u * 256] = r;
  }
}

// ---------------------------------------------------------------------------
// FP8 GEMM at the MX rate (mfma_scale_f32_16x16x128_f8f6f4, unit e8m0 scales
// = numerically plain fp8 dot + fp32 acc), R4: single-barrier double-buffered
// pipeline. Per K-iter: [barrier] [issue async loads for tile k+1 into buf
// (k+1)&1] [compute tile k from buf k&1]. The compiler's vmcnt(0) drain at
// the NEXT barrier lands a full compute-phase after issue — staging overlaps
// compute, unlike the 2-barrier m97 shape where the drain is immediate.
// 512 threads = 8 waves (2x4), each wave a 64x32 C-block (4x2 MFMA tiles);
// 16 waves/CU (2 blocks) for MFMA/VMEM interleave.
//
// LDS rows of 128B = 8 chunks of 16B, XOR-swizzled: logical chunk c of row r
// at physical chunk c ^ (r&7). Staging (LDS dst pinned to tid*16): thread t
// covers row t>>3 (+64 on 2nd load), phys chunk t&7 -> fetches global chunk
// (t&7)^((t>>3)&7) (lane constant). Read-side term: frow&7.
// Fragment layouts (HW-verified m89/m148): A: lane holds
// A[m=lane&15][k=(lane>>4)*32 + j], j=0..31; C/D: col=lane&15,
// row=(lane>>4)*4+reg (shape-determined).
// ---------------------------------------------------------------------------
__launch_bounds__(512, 4)
__global__ void gemm_fp8(const unsigned char* __restrict__ qx,
                         const unsigned char* __restrict__ qw,
                         const float* __restrict__ bias,
                         const float* __restrict__ scalars,
                         float* __restrict__ out) {
  __shared__ __align__(16) unsigned char As[2 * BM * BK];  // 2 x 16 KiB
  __shared__ __align__(16) unsigned char Bs[2 * BN * BK];  // 2 x 16 KiB

  const int tid = threadIdx.x;   // 0..511
  const int lane = tid & 63;
  const int wv = tid >> 6;       // 0..7
  const int wm = (wv & 1) * 64;  // wave M offset (2 rows of waves)
  const int wn = (wv >> 1) * 32; // wave N offset (4 cols of waves)
  const int bm0 = blockIdx.y * BM;
  const int bn0 = blockIdx.x * BN;

  // Staging source map: 4 async16 per thread per tile-pair (A lo/hi, B lo/hi)
  const int srow = tid >> 3;                          // 0..63
  const int sc = ((tid & 7) ^ ((tid >> 3) & 7)) << 4; // swizzled source col
  const unsigned char* gA0 = qx + (size_t)(bm0 + srow) * Kdim + sc;
  const unsigned char* gB0 = qw + (size_t)(bn0 + srow) * Kdim + sc;
  const size_t rstep = (size_t)64 * Kdim;
  const int lslot = tid * 16;

  floatx4 acc[4][2];
#pragma unroll
  for (int i = 0; i < 4; i++)
#pragma unroll
    for (int j = 0; j < 2; j++) acc[i][j] = (floatx4){0.f, 0.f, 0.f, 0.f};

  // Fragment read constants
  const int frow = lane & 15;
  const int h = lane >> 4;                   // k-block 0..3 (32B each)
  const int fr7 = frow & 7;
  const int kc0 = ((2 * h) ^ fr7) << 4;      // phys offset of logical chunk 2h
  const int kc1 = ((2 * h + 1) ^ fr7) << 4;  // phys offset of chunk 2h+1

  // Prologue: stage tile 0 into buffer 0
  async_load16(gA0, As + lslot);
  async_load16(gA0 + rstep, As + 8192 + lslot);
  async_load16(gB0, Bs + lslot);
  async_load16(gB0 + rstep, Bs + 8192 + lslot);

  for (int kt = 0; kt < KT; ++kt) {
    __syncthreads();  // drains loads issued LAST iter (a full compute ago)
    const int buf = (kt & 1) * 16384;
    if (kt + 1 < KT) {
      const int nbuf = ((kt + 1) & 1) * 16384;
      const int k0 = (kt + 1) * BK;
      async_load16(gA0 + k0, As + nbuf + lslot);
      async_load16(gA0 + k0 + rstep, As + nbuf + 8192 + lslot);
      async_load16(gB0 + k0, Bs + nbuf + lslot);
      async_load16(gB0 + k0 + rstep, Bs + nbuf + 8192 + lslot);
    }

    intx8 af[4], bf[2];
#pragma unroll
    for (int t = 0; t < 4; t++) {
      const unsigned char* ra = As + buf + (wm + t * 16 + frow) * BK;
      intx4 lo = *(const intx4*)(ra + kc0);
      intx4 hi = *(const intx4*)(ra + kc1);
      af[t] = __builtin_shufflevector(lo, hi, 0, 1, 2, 3, 4, 5, 6, 7);
    }
#pragma unroll
    for (int u = 0; u < 2; u++) {
      const unsigned char* rb = Bs + buf + (wn + u * 16 + frow) * BK;
      intx4 lo = *(const intx4*)(rb + kc0);
      intx4 hi = *(const intx4*)(rb + kc1);
      bf[u] = __builtin_shufflevector(lo, hi, 0, 1, 2, 3, 4, 5, 6, 7);
    }
#pragma unroll
    for (int i = 0; i < 4; i++)
#pragma unroll
      for (int j = 0; j < 2; j++)
        acc[i][j] = __builtin_amdgcn_mfma_scale_f32_16x16x128_f8f6f4(
            af[i], bf[j], acc[i][j], 0 /*A=fp8*/, 0 /*B=fp8*/,
            0, 0x7F7F7F7F, 0, 0x7F7F7F7F);  // unit scales (e8m0 127 = 2^0)
  }

  // Dequant scale, mirroring reference fp32 arithmetic exactly.
  float ax = fmaxf(scalars[0], 1e-12f);
  float aw = fmaxf(scalars[1], 1e-12f);
  float cs = (1.0f / (FP8_MAX_F / ax)) * (1.0f / (FP8_MAX_F / aw));

  const int crow = bm0 + wm + (lane >> 4) * 4;
  const int ccol = bn0 + wn + (lane & 15);
#pragma unroll
  for (int j = 0; j < 2; j++) {
    float bv = bias[ccol + j * 16];
#pragma unroll
    for (int i = 0; i < 4; i++) {
#pragma unroll
      for (int r = 0; r < 4; r++) {
        out[(size_t)(crow + i * 16 + r) * Ndim + (ccol + j * 16)] =
            acc[i][j][r] * cs + bv;
      }
    }
  }
}

extern "C" void kernel_launch(void* const* d_in, const int* in_sizes, int n_in,
                              void* d_out, int out_size, void* d_ws, size_t ws_size,
                              hipStream_t stream) {
  const float* x = (const float*)d_in[0];     // [M,K] fp32
  const float* w = (const float*)d_in[1];     // [N,K] fp32
  const float* bias = (const float*)d_in[2];  // [N] fp32
  float* out = (float*)d_out;                 // [M,N] fp32

  // Workspace: partials (3072 f) | scalars (2 f) | pad to 32 KiB | qx | qw
  float* part = (float*)d_ws;
  float* scalars = part + 4096;
  unsigned char* qx = (unsigned char*)d_ws + 32768;
  unsigned char* qw = qx + (size_t)Mdim * Kdim;

  amax_partials<<<A_XB + A_WB, 256, 0, stream>>>(x, w, part);
  quant_both<<<Q_XB + Q_WB, 256, 0, stream>>>(x, w, part,
                                              (unsigned int*)qx, (unsigned int*)qw,
                                              scalars);
  dim3 grid(Ndim / BN, Mdim / BM);  // 32 x 16 = 512 blocks, 512 threads
  gemm_fp8<<<grid, 512, 0, stream>>>(qx, qw, bias, scalars, out);
}